// Round 6
// baseline (88.989 us; speedup 1.0000x reference)
//
#include <hip/hip_runtime.h>

// DETR-style post-process: softmax scores/labels + box scale + per-image greedy NMS.
// Outputs (flat f32, concatenated): scores[B*Q] | labels[B*Q] | boxes[B*Q*4] | keep[B*Q]
//
// Pipeline (4 graph nodes):
//  k_score_box : per-(b,q) wave softmax/argmax + box conversion + sort key (HBM-bound)
//  k_rank      : counting-rank via scalar-broadcast key scan -> ws      (VALU, ~2-3us)
//  k_mask      : suppression bitmask, 4 tri-tiles per 256-thr block     (VALU-bound)
//  k_scan      : 1 wave/image, barrier-free ballot greedy scan          (serial floor)

constexpr int kB  = 32;
constexpr int kQ  = 1024;
constexpr int kNC = 256;
constexpr int kBQ = kB * kQ;
constexpr float kIouThr = 0.5f;

typedef unsigned long long u64;
typedef unsigned int u32;

// IoU > thr with numpy-identical op ordering (no FMA contraction, exact division).
__device__ __forceinline__ bool iou_gt(const float4& a, float aa,
                                       const float4& b, float ba) {
  float lx = fmaxf(a.x, b.x);
  float ly = fmaxf(a.y, b.y);
  float rx = fminf(a.z, b.z);
  float ry = fminf(a.w, b.w);
  float w  = fmaxf(__fsub_rn(rx, lx), 0.0f);
  float h  = fmaxf(__fsub_rn(ry, ly), 0.0f);
  float inter = __fmul_rn(w, h);
  float uni   = __fsub_rn(__fadd_rn(aa, ba), inter);
  float iou   = __fdiv_rn(inter, fmaxf(uni, 1e-9f));
  return iou > kIouThr;
}

// One wave (64 lanes) per (b,q): 256 logits -> softmax score/label; box cxcywh->xyxy*scale.
// Also emits the u64 stable-descending sort key for k_rank (from the same score register).
__global__ void k_score_box(const float* __restrict__ logits,
                            const float* __restrict__ pboxes,
                            const int* __restrict__ ts,
                            float* __restrict__ out,
                            u64* __restrict__ keys) {
  int gw   = (int)((blockIdx.x * blockDim.x + threadIdx.x) >> 6);
  int lane = (int)(threadIdx.x & 63);
  if (gw >= kBQ) return;

  float4 v = reinterpret_cast<const float4*>(logits)[gw * (kNC / 4) + lane];

  // foreground (first 255 classes) max + argmax, first-occurrence tie-break
  float fw = (lane == 63) ? -INFINITY : v.w;
  float fm = v.x; int fi = lane * 4;
  if (v.y > fm) { fm = v.y; fi = lane * 4 + 1; }
  if (v.z > fm) { fm = v.z; fi = lane * 4 + 2; }
  if (fw  > fm) { fm = fw;  fi = lane * 4 + 3; }
  for (int off = 32; off > 0; off >>= 1) {
    float om = __shfl_xor(fm, off, 64);
    int   oi = __shfl_xor(fi, off, 64);
    if (om > fm || (om == fm && oi < fi)) { fm = om; fi = oi; }
  }

  float last = __shfl(v.w, 63, 64);     // logit of class 255 (bg)
  float m = fmaxf(fm, last);            // max over all 256 (exact)

  float s = expf(v.x - m) + expf(v.y - m) + expf(v.z - m) + expf(v.w - m);
  for (int off = 32; off > 0; off >>= 1) s += __shfl_xor(s, off, 64);

  if (lane == 0) {
    float sc = expf(fm - m) / s;
    out[gw]       = sc;
    out[kBQ + gw] = (float)fi;
    // stable descending key: scores > 0 -> bit-monotone; low 32 = in-image idx
    keys[gw] = ((u64)(~__float_as_uint(sc)) << 32) | (u32)(gw & (kQ - 1));

    float4 pb = reinterpret_cast<const float4*>(pboxes)[gw];
    int bi = gw >> 10;
    float ih = (float)ts[bi * 2 + 0];
    float iw = (float)ts[bi * 2 + 1];
    float hw = __fmul_rn(0.5f, pb.z);
    float hh = __fmul_rn(0.5f, pb.w);
    float x0 = __fmul_rn(__fsub_rn(pb.x, hw), iw);
    float y0 = __fmul_rn(__fsub_rn(pb.y, hh), ih);
    float x1 = __fmul_rn(__fadd_rn(pb.x, hw), iw);
    float y1 = __fmul_rn(__fadd_rn(pb.y, hh), ih);
    reinterpret_cast<float4*>(out + 2 * kBQ)[gw] = make_float4(x0, y0, x1, y1);
  }
}

// Counting rank: rank_j = #{k : key_k < key_j}. Keys scanned with a wave-uniform
// index -> scalar s_load broadcast (no DS port traffic, no LDS key staging).
// grid (32, 8) x 128 threads: 128 j's per block, 1 block/CU.
__global__ void __launch_bounds__(128) k_rank(const u64* __restrict__ keys,
                                              const float* __restrict__ out,
                                              u32* __restrict__ order,
                                              float4* __restrict__ sbox,
                                              float* __restrict__ sarea) {
  const int b = (int)blockIdx.x, sb = (int)blockIdx.y, tid = (int)threadIdx.x;
  const u64* gk = keys + b * kQ;

  const int j = sb * 128 + tid;
  const u64 kj = gk[j];
  int cnt = 0;
  #pragma unroll 8
  for (int k = 0; k < kQ; ++k) cnt += (int)(gk[k] < kj);   // gk[k] uniform -> s_load

  float4 bx = reinterpret_cast<const float4*>(out + 2 * kBQ)[b * kQ + j];
  order[b * kQ + cnt] = (u32)j;
  sbox[b * kQ + cnt]  = bx;
  sarea[b * kQ + cnt] = __fmul_rn(__fsub_rn(bx.z, bx.x), __fsub_rn(bx.w, bx.y));
}

// Suppression bitmask, column form: maskT[b][c][j] bit l = (i=c*64+l < j) && IoU(i,j)>thr.
// 4 waves/block, one 64x64 tri-tile per wave: grid (32, 34), r = by*4+wv in [0,136).
__global__ void __launch_bounds__(256) k_mask(const float4* __restrict__ sbox,
                                              const float* __restrict__ sarea,
                                              u64* __restrict__ maskT) {
  const int b = (int)blockIdx.x;
  const int wv = (int)(threadIdx.x >> 6), lane = (int)(threadIdx.x & 63);
  const int r = (int)blockIdx.y * 4 + wv;           // 0..135, all valid

  // linear tri index -> (jb, c), jb >= c
  int jb = (int)((sqrtf((float)(8 * r + 1)) - 1.0f) * 0.5f);
  while ((jb + 1) * (jb + 2) / 2 <= r) ++jb;
  while (jb * (jb + 1) / 2 > r) --jb;
  const int c = r - jb * (jb + 1) / 2;

  __shared__ float4 iboxS[4][64];
  __shared__ float  iareaS[4][64];
  iboxS[wv][lane]  = sbox[b * kQ + c * 64 + lane];
  iareaS[wv][lane] = sarea[b * kQ + c * 64 + lane];
  // wave-private LDS slice: in-wave ds ordering suffices, no block barrier.

  const int j = jb * 64 + lane;
  const float4 bj = sbox[b * kQ + j];
  const float  aj = sarea[b * kQ + j];

  u32 wlo = 0, whi = 0;
  if (c < jb) {                                     // full tile: every i < j
    #pragma unroll 4
    for (int l = 0; l < 32; ++l)
      wlo |= ((u32)iou_gt(iboxS[wv][l], iareaS[wv][l], bj, aj)) << l;
    #pragma unroll 4
    for (int l = 0; l < 32; ++l)
      whi |= ((u32)iou_gt(iboxS[wv][l + 32], iareaS[wv][l + 32], bj, aj)) << l;
  } else {                                          // diagonal: strict l < lane
    #pragma unroll 4
    for (int l = 0; l < 32; ++l)
      wlo |= ((u32)((l < lane) && iou_gt(iboxS[wv][l], iareaS[wv][l], bj, aj))) << l;
    #pragma unroll 4
    for (int l = 0; l < 32; ++l)
      whi |= ((u32)((l + 32 < lane) && iou_gt(iboxS[wv][l + 32], iareaS[wv][l + 32], bj, aj))) << l;
  }
  maskT[(b * 16 + c) * kQ + j] = ((u64)whi << 32) | wlo;
}

// Barrier-free greedy scan: one wave per image. Stage the image's 128KB maskT
// in LDS, then per chunk c: ballot-driven greedy (one iteration per KEPT box:
// alive only grows, so any lane with (diag & alive)!=0 is suppressed forever),
// then fold alive into later chunks with one LDS AND per (lane, chunk).
__global__ void __launch_bounds__(256) k_scan(const u64* __restrict__ maskT,
                                              const u32* __restrict__ order,
                                              float* __restrict__ out) {
  __shared__ u64 lm[16 * kQ];                       // 128 KB (1 block/CU; 32 blocks)
  const int b = (int)blockIdx.x, tid = (int)threadIdx.x;

  const uint4* src = (const uint4*)(maskT + (size_t)b * 16 * kQ);
  uint4* dst = (uint4*)lm;
  #pragma unroll 4
  for (int t = tid; t < 16 * kQ / 2; t += 256) dst[t] = src[t];
  __syncthreads();
  if (tid >= 64) return;                            // waves 1-3 only helped copy
  const int lane = tid;

  u32 sbits = 0;                                    // bit k: j=k*64+lane suppressed
  u32 keepbits = 0;
  for (int c = 0; c < 16; ++c) {
    u64 d = lm[c * kQ + c * 64 + lane];             // diag word (bits i<lane only)
    u64 todo = ~__ballot(((sbits >> c) & 1u) != 0u);
    u64 alive = 0ull;
    while (true) {
      u64 bal = __ballot((d & alive) == 0ull) & todo;
      if (bal == 0ull) break;
      int l = __builtin_ctzll(bal);                 // lowest eligible rank
      alive |= 1ull << l;
      todo &= ~((2ull << l) - 1ull);                // lanes <l proven suppressed; l kept
    }
    keepbits |= ((u32)((alive >> lane) & 1ull)) << c;
    for (int k = c + 1; k < 16; ++k) {              // fold kept set into later chunks
      u64 w = lm[c * kQ + k * 64 + lane];
      if ((w & alive) != 0ull) sbits |= 1u << k;
    }
  }

  const u32* ord = order + b * kQ;
  float* kout = out + 6 * kBQ + b * kQ;
  #pragma unroll
  for (int k = 0; k < 16; ++k) {
    u32 oj = ord[k * 64 + lane];
    kout[oj] = ((keepbits >> k) & 1u) ? 1.0f : 0.0f;
  }
}

extern "C" void kernel_launch(void* const* d_in, const int* in_sizes, int n_in,
                              void* d_out, int out_size, void* d_ws, size_t ws_size,
                              hipStream_t stream) {
  const float* logits = (const float*)d_in[0];
  const float* pboxes = (const float*)d_in[1];
  const int*   ts     = (const int*)d_in[2];
  float* out = (float*)d_out;

  // ws layout (≈5 MB): maskT 4MB | order 128KB | sbox 512KB | sarea 128KB | keys 256KB
  char* ws = (char*)d_ws;
  u64*    maskT = (u64*)ws;
  u32*    order = (u32*)(ws + (4 << 20));
  float4* sbox  = (float4*)(ws + (4 << 20) + (128 << 10));
  float*  sarea = (float*)(ws + (4 << 20) + (640 << 10));
  u64*    keys  = (u64*)(ws + (4 << 20) + (768 << 10));

  dim3 g1(kBQ / 4), t1(256);
  k_score_box<<<g1, t1, 0, stream>>>(logits, pboxes, ts, out, keys);

  dim3 g2(kB, kQ / 128), t2(128);
  k_rank<<<g2, t2, 0, stream>>>(keys, out, order, sbox, sarea);

  dim3 g3(kB, 34), t3(256);
  k_mask<<<g3, t3, 0, stream>>>(sbox, sarea, maskT);

  k_scan<<<kB, 256, 0, stream>>>(maskT, order, out);
}

// Round 7
// 83.189 us; speedup vs baseline: 1.0697x; 1.0697x over previous
//
#include <hip/hip_runtime.h>

// DETR-style post-process: softmax scores/labels + box scale + per-image greedy NMS.
// Outputs (flat f32, concatenated): scores[B*Q] | labels[B*Q] | boxes[B*Q*4] | keep[B*Q]
//
// Pipeline (4 graph nodes):
//  k_score_box : per-(b,q) wave softmax/argmax + box conversion + sort key (HBM-bound)
//  k_rank      : counting-rank, LDS-broadcast key scan -> ws          (VALU, cheap)
//  k_mask      : suppression bitmask, 4 tri-tiles per 256-thr block   (VALU-bound)
//  k_scan      : 16-wave pipelined greedy scan, register folds        (serial floor)

constexpr int kB  = 32;
constexpr int kQ  = 1024;
constexpr int kNC = 256;
constexpr int kBQ = kB * kQ;
constexpr float kIouThr = 0.5f;

typedef unsigned long long u64;
typedef unsigned int u32;

// IoU > thr with numpy-identical op ordering (no FMA contraction, exact division).
__device__ __forceinline__ bool iou_gt(const float4& a, float aa,
                                       const float4& b, float ba) {
  float lx = fmaxf(a.x, b.x);
  float ly = fmaxf(a.y, b.y);
  float rx = fminf(a.z, b.z);
  float ry = fminf(a.w, b.w);
  float w  = fmaxf(__fsub_rn(rx, lx), 0.0f);
  float h  = fmaxf(__fsub_rn(ry, ly), 0.0f);
  float inter = __fmul_rn(w, h);
  float uni   = __fsub_rn(__fadd_rn(aa, ba), inter);
  float iou   = __fdiv_rn(inter, fmaxf(uni, 1e-9f));
  return iou > kIouThr;
}

// One wave (64 lanes) per (b,q): 256 logits -> softmax score/label; box cxcywh->xyxy*scale.
// Also emits the u64 stable-descending sort key for k_rank (from the same score register).
__global__ void k_score_box(const float* __restrict__ logits,
                            const float* __restrict__ pboxes,
                            const int* __restrict__ ts,
                            float* __restrict__ out,
                            u64* __restrict__ keys) {
  int gw   = (int)((blockIdx.x * blockDim.x + threadIdx.x) >> 6);
  int lane = (int)(threadIdx.x & 63);
  if (gw >= kBQ) return;

  float4 v = reinterpret_cast<const float4*>(logits)[gw * (kNC / 4) + lane];

  // foreground (first 255 classes) max + argmax, first-occurrence tie-break
  float fw = (lane == 63) ? -INFINITY : v.w;
  float fm = v.x; int fi = lane * 4;
  if (v.y > fm) { fm = v.y; fi = lane * 4 + 1; }
  if (v.z > fm) { fm = v.z; fi = lane * 4 + 2; }
  if (fw  > fm) { fm = fw;  fi = lane * 4 + 3; }
  for (int off = 32; off > 0; off >>= 1) {
    float om = __shfl_xor(fm, off, 64);
    int   oi = __shfl_xor(fi, off, 64);
    if (om > fm || (om == fm && oi < fi)) { fm = om; fi = oi; }
  }

  float last = __shfl(v.w, 63, 64);     // logit of class 255 (bg)
  float m = fmaxf(fm, last);            // max over all 256 (exact)

  float s = expf(v.x - m) + expf(v.y - m) + expf(v.z - m) + expf(v.w - m);
  for (int off = 32; off > 0; off >>= 1) s += __shfl_xor(s, off, 64);

  if (lane == 0) {
    float sc = expf(fm - m) / s;
    out[gw]       = sc;
    out[kBQ + gw] = (float)fi;
    // stable descending key: scores > 0 -> bit-monotone; low 32 = in-image idx
    keys[gw] = ((u64)(~__float_as_uint(sc)) << 32) | (u32)(gw & (kQ - 1));

    float4 pb = reinterpret_cast<const float4*>(pboxes)[gw];
    int bi = gw >> 10;
    float ih = (float)ts[bi * 2 + 0];
    float iw = (float)ts[bi * 2 + 1];
    float hw = __fmul_rn(0.5f, pb.z);
    float hh = __fmul_rn(0.5f, pb.w);
    float x0 = __fmul_rn(__fsub_rn(pb.x, hw), iw);
    float y0 = __fmul_rn(__fsub_rn(pb.y, hh), ih);
    float x1 = __fmul_rn(__fadd_rn(pb.x, hw), iw);
    float y1 = __fmul_rn(__fadd_rn(pb.y, hh), ih);
    reinterpret_cast<float4*>(out + 2 * kBQ)[gw] = make_float4(x0, y0, x1, y1);
  }
}

// Counting rank: rank_j = #{k : key_k < key_j} over LDS-staged keys (broadcast reads).
// Exactly reproduces stable argsort(-scores). grid (32,4) x 256.
__global__ void __launch_bounds__(256) k_rank(const u64* __restrict__ keys,
                                              const float* __restrict__ out,
                                              u32* __restrict__ order,
                                              float4* __restrict__ sbox,
                                              float* __restrict__ sarea) {
  __shared__ u64 ks[kQ];
  const int b = (int)blockIdx.x, sb = (int)blockIdx.y, tid = (int)threadIdx.x;

  for (int t = tid; t < kQ; t += 256) ks[t] = keys[b * kQ + t];
  __syncthreads();

  const int j = sb * 256 + tid;
  const u64 kj = ks[j];
  int cnt = 0;
  #pragma unroll 8
  for (int k = 0; k < kQ; ++k) cnt += (int)(ks[k] < kj);  // wave-uniform -> broadcast

  float4 bx = reinterpret_cast<const float4*>(out + 2 * kBQ)[b * kQ + j];
  order[b * kQ + cnt] = (u32)j;
  sbox[b * kQ + cnt]  = bx;
  sarea[b * kQ + cnt] = __fmul_rn(__fsub_rn(bx.z, bx.x), __fsub_rn(bx.w, bx.y));
}

// Suppression bitmask, column form: maskT[b][c][j] bit l = (i=c*64+l < j) && IoU(i,j)>thr.
// 4 waves/block, one 64x64 tri-tile per wave: grid (32, 34), r = by*4+wv in [0,136).
__global__ void __launch_bounds__(256) k_mask(const float4* __restrict__ sbox,
                                              const float* __restrict__ sarea,
                                              u64* __restrict__ maskT) {
  const int b = (int)blockIdx.x;
  const int wv = (int)(threadIdx.x >> 6), lane = (int)(threadIdx.x & 63);
  const int r = (int)blockIdx.y * 4 + wv;           // 0..135, all valid

  // linear tri index -> (jb, c), jb >= c
  int jb = (int)((sqrtf((float)(8 * r + 1)) - 1.0f) * 0.5f);
  while ((jb + 1) * (jb + 2) / 2 <= r) ++jb;
  while (jb * (jb + 1) / 2 > r) --jb;
  const int c = r - jb * (jb + 1) / 2;

  __shared__ float4 iboxS[4][64];
  __shared__ float  iareaS[4][64];
  iboxS[wv][lane]  = sbox[b * kQ + c * 64 + lane];
  iareaS[wv][lane] = sarea[b * kQ + c * 64 + lane];
  // wave-private LDS slice: in-wave ds ordering suffices, no block barrier.

  const int j = jb * 64 + lane;
  const float4 bj = sbox[b * kQ + j];
  const float  aj = sarea[b * kQ + j];

  u32 wlo = 0, whi = 0;
  if (c < jb) {                                     // full tile: every i < j
    #pragma unroll 4
    for (int l = 0; l < 32; ++l)
      wlo |= ((u32)iou_gt(iboxS[wv][l], iareaS[wv][l], bj, aj)) << l;
    #pragma unroll 4
    for (int l = 0; l < 32; ++l)
      whi |= ((u32)iou_gt(iboxS[wv][l + 32], iareaS[wv][l + 32], bj, aj)) << l;
  } else {                                          // diagonal: strict l < lane
    #pragma unroll 4
    for (int l = 0; l < 32; ++l)
      wlo |= ((u32)((l < lane) && iou_gt(iboxS[wv][l], iareaS[wv][l], bj, aj))) << l;
    #pragma unroll 4
    for (int l = 0; l < 32; ++l)
      whi |= ((u32)((l + 32 < lane) && iou_gt(iboxS[wv][l + 32], iareaS[wv][l + 32], bj, aj))) << l;
  }
  maskT[(b * 16 + c) * kQ + j] = ((u64)whi << 32) | wlo;
}

// Pipelined greedy scan: one block (16 waves) per image; wave k owns chunk k.
// Wave k preloads its fold column (c,k) c<k + diag into REGISTERS (static unroll),
// spins on a workgroup-scope LDS counter for alive_c, folds in-register, then runs
// the ballot-greedy loop (one iteration per kept box) and publishes alive_k.
__global__ void __launch_bounds__(1024) k_scan(const u64* __restrict__ maskT,
                                               const u32* __restrict__ order,
                                               float* __restrict__ out) {
  __shared__ u64 aliveS[16];
  __shared__ u32 doneS;
  const int b = (int)blockIdx.x, tid = (int)threadIdx.x;
  const int lane = tid & 63, k = tid >> 6;          // wave id == chunk id

  // upfront preload, all static-indexed -> registers, one batch of loads
  const u64* mb = maskT + (size_t)(b * 16) * kQ;
  u64 w[15];
  #pragma unroll
  for (int c = 0; c < 15; ++c)
    w[c] = (c < k) ? mb[c * kQ + k * 64 + lane] : 0ull;
  u64 d = mb[k * kQ + k * 64 + lane];               // diag word (bits i<lane only)
  u32 oj = order[b * kQ + k * 64 + lane];

  if (tid == 0) doneS = 0;
  __syncthreads();

  // fold earlier chunks' kept sets as they are published
  bool supp = false;
  #pragma unroll
  for (int c = 0; c < 15; ++c) {
    if (c >= k) break;                              // wave-uniform
    u32 dn;
    do {
      dn = __hip_atomic_load(&doneS, __ATOMIC_ACQUIRE, __HIP_MEMORY_SCOPE_WORKGROUP);
    } while ((int)dn <= c);
    supp = supp || ((w[c] & aliveS[c]) != 0ull);
  }

  // my turn (doneS >= k now): ballot-greedy within chunk k
  u64 todo = ~__ballot(supp);
  u64 alive = 0ull;
  while (true) {
    u64 bal = __ballot((d & alive) == 0ull) & todo;
    if (bal == 0ull) break;
    int l = __builtin_ctzll(bal);                   // lowest eligible rank
    alive |= 1ull << l;
    todo &= ~((2ull << l) - 1ull);                  // lanes <l proven suppressed; l kept
  }
  if (lane == 0) {
    aliveS[k] = alive;
    __hip_atomic_store(&doneS, (u32)(k + 1), __ATOMIC_RELEASE, __HIP_MEMORY_SCOPE_WORKGROUP);
  }

  bool keep = ((alive >> lane) & 1ull) != 0ull;
  out[6 * kBQ + b * kQ + (int)oj] = keep ? 1.0f : 0.0f;
}

extern "C" void kernel_launch(void* const* d_in, const int* in_sizes, int n_in,
                              void* d_out, int out_size, void* d_ws, size_t ws_size,
                              hipStream_t stream) {
  const float* logits = (const float*)d_in[0];
  const float* pboxes = (const float*)d_in[1];
  const int*   ts     = (const int*)d_in[2];
  float* out = (float*)d_out;

  // ws layout (≈5 MB): maskT 4MB | order 128KB | sbox 512KB | sarea 128KB | keys 256KB
  char* ws = (char*)d_ws;
  u64*    maskT = (u64*)ws;
  u32*    order = (u32*)(ws + (4 << 20));
  float4* sbox  = (float4*)(ws + (4 << 20) + (128 << 10));
  float*  sarea = (float*)(ws + (4 << 20) + (640 << 10));
  u64*    keys  = (u64*)(ws + (4 << 20) + (768 << 10));

  dim3 g1(kBQ / 4), t1(256);
  k_score_box<<<g1, t1, 0, stream>>>(logits, pboxes, ts, out, keys);

  dim3 g2(kB, kQ / 256), t2(256);
  k_rank<<<g2, t2, 0, stream>>>(keys, out, order, sbox, sarea);

  dim3 g3(kB, 34), t3(256);
  k_mask<<<g3, t3, 0, stream>>>(sbox, sarea, maskT);

  k_scan<<<kB, 1024, 0, stream>>>(maskT, order, out);
}

// Round 8
// 61.175 us; speedup vs baseline: 1.4547x; 1.3598x over previous
//
#include <hip/hip_runtime.h>

// DETR-style post-process: softmax scores/labels + box scale + per-image greedy NMS.
// Outputs (flat f32, concatenated): scores[B*Q] | labels[B*Q] | boxes[B*Q*4] | keep[B*Q]
//
// Pipeline (4 graph nodes):
//  k_score_box : per-(b,q) wave softmax/argmax + box conversion + sort key (HBM-bound)
//  k_rank      : counting-rank, LDS-broadcast key scan -> ws          (VALU, cheap)
//  k_mask      : suppression bitmask, 4 tri-tiles per 256-thr block   (VALU-bound)
//  k_scan      : 16-wave pipelined scan + layered fixpoint per chunk  (serial floor)

constexpr int kB  = 32;
constexpr int kQ  = 1024;
constexpr int kNC = 256;
constexpr int kBQ = kB * kQ;
constexpr float kIouThr = 0.5f;

typedef unsigned long long u64;
typedef unsigned int u32;

// IoU > thr with numpy-identical op ordering (no FMA contraction, exact division).
__device__ __forceinline__ bool iou_gt(const float4& a, float aa,
                                       const float4& b, float ba) {
  float lx = fmaxf(a.x, b.x);
  float ly = fmaxf(a.y, b.y);
  float rx = fminf(a.z, b.z);
  float ry = fminf(a.w, b.w);
  float w  = fmaxf(__fsub_rn(rx, lx), 0.0f);
  float h  = fmaxf(__fsub_rn(ry, ly), 0.0f);
  float inter = __fmul_rn(w, h);
  float uni   = __fsub_rn(__fadd_rn(aa, ba), inter);
  float iou   = __fdiv_rn(inter, fmaxf(uni, 1e-9f));
  return iou > kIouThr;
}

// One wave (64 lanes) per (b,q): 256 logits -> softmax score/label; box cxcywh->xyxy*scale.
// Also emits the u64 stable-descending sort key for k_rank (from the same score register).
__global__ void k_score_box(const float* __restrict__ logits,
                            const float* __restrict__ pboxes,
                            const int* __restrict__ ts,
                            float* __restrict__ out,
                            u64* __restrict__ keys) {
  int gw   = (int)((blockIdx.x * blockDim.x + threadIdx.x) >> 6);
  int lane = (int)(threadIdx.x & 63);
  if (gw >= kBQ) return;

  float4 v = reinterpret_cast<const float4*>(logits)[gw * (kNC / 4) + lane];

  // foreground (first 255 classes) max + argmax, first-occurrence tie-break
  float fw = (lane == 63) ? -INFINITY : v.w;
  float fm = v.x; int fi = lane * 4;
  if (v.y > fm) { fm = v.y; fi = lane * 4 + 1; }
  if (v.z > fm) { fm = v.z; fi = lane * 4 + 2; }
  if (fw  > fm) { fm = fw;  fi = lane * 4 + 3; }
  for (int off = 32; off > 0; off >>= 1) {
    float om = __shfl_xor(fm, off, 64);
    int   oi = __shfl_xor(fi, off, 64);
    if (om > fm || (om == fm && oi < fi)) { fm = om; fi = oi; }
  }

  float last = __shfl(v.w, 63, 64);     // logit of class 255 (bg)
  float m = fmaxf(fm, last);            // max over all 256 (exact)

  float s = expf(v.x - m) + expf(v.y - m) + expf(v.z - m) + expf(v.w - m);
  for (int off = 32; off > 0; off >>= 1) s += __shfl_xor(s, off, 64);

  if (lane == 0) {
    float sc = expf(fm - m) / s;
    out[gw]       = sc;
    out[kBQ + gw] = (float)fi;
    // stable descending key: scores > 0 -> bit-monotone; low 32 = in-image idx
    keys[gw] = ((u64)(~__float_as_uint(sc)) << 32) | (u32)(gw & (kQ - 1));

    float4 pb = reinterpret_cast<const float4*>(pboxes)[gw];
    int bi = gw >> 10;
    float ih = (float)ts[bi * 2 + 0];
    float iw = (float)ts[bi * 2 + 1];
    float hw = __fmul_rn(0.5f, pb.z);
    float hh = __fmul_rn(0.5f, pb.w);
    float x0 = __fmul_rn(__fsub_rn(pb.x, hw), iw);
    float y0 = __fmul_rn(__fsub_rn(pb.y, hh), ih);
    float x1 = __fmul_rn(__fadd_rn(pb.x, hw), iw);
    float y1 = __fmul_rn(__fadd_rn(pb.y, hh), ih);
    reinterpret_cast<float4*>(out + 2 * kBQ)[gw] = make_float4(x0, y0, x1, y1);
  }
}

// Counting rank: rank_j = #{k : key_k < key_j} over LDS-staged keys (broadcast reads).
// Exactly reproduces stable argsort(-scores). grid (32,4) x 256.
__global__ void __launch_bounds__(256) k_rank(const u64* __restrict__ keys,
                                              const float* __restrict__ out,
                                              u32* __restrict__ order,
                                              float4* __restrict__ sbox,
                                              float* __restrict__ sarea) {
  __shared__ u64 ks[kQ];
  const int b = (int)blockIdx.x, sb = (int)blockIdx.y, tid = (int)threadIdx.x;

  for (int t = tid; t < kQ; t += 256) ks[t] = keys[b * kQ + t];
  __syncthreads();

  const int j = sb * 256 + tid;
  const u64 kj = ks[j];
  int cnt = 0;
  #pragma unroll 8
  for (int k = 0; k < kQ; ++k) cnt += (int)(ks[k] < kj);  // wave-uniform -> broadcast

  float4 bx = reinterpret_cast<const float4*>(out + 2 * kBQ)[b * kQ + j];
  order[b * kQ + cnt] = (u32)j;
  sbox[b * kQ + cnt]  = bx;
  sarea[b * kQ + cnt] = __fmul_rn(__fsub_rn(bx.z, bx.x), __fsub_rn(bx.w, bx.y));
}

// Suppression bitmask, column form: maskT[b][c][j] bit l = (i=c*64+l < j) && IoU(i,j)>thr.
// 4 waves/block, one 64x64 tri-tile per wave: grid (32, 34), r = by*4+wv in [0,136).
__global__ void __launch_bounds__(256) k_mask(const float4* __restrict__ sbox,
                                              const float* __restrict__ sarea,
                                              u64* __restrict__ maskT) {
  const int b = (int)blockIdx.x;
  const int wv = (int)(threadIdx.x >> 6), lane = (int)(threadIdx.x & 63);
  const int r = (int)blockIdx.y * 4 + wv;           // 0..135, all valid

  // linear tri index -> (jb, c), jb >= c
  int jb = (int)((sqrtf((float)(8 * r + 1)) - 1.0f) * 0.5f);
  while ((jb + 1) * (jb + 2) / 2 <= r) ++jb;
  while (jb * (jb + 1) / 2 > r) --jb;
  const int c = r - jb * (jb + 1) / 2;

  __shared__ float4 iboxS[4][64];
  __shared__ float  iareaS[4][64];
  iboxS[wv][lane]  = sbox[b * kQ + c * 64 + lane];
  iareaS[wv][lane] = sarea[b * kQ + c * 64 + lane];
  // wave-private LDS slice: in-wave ds ordering suffices, no block barrier.

  const int j = jb * 64 + lane;
  const float4 bj = sbox[b * kQ + j];
  const float  aj = sarea[b * kQ + j];

  u32 wlo = 0, whi = 0;
  if (c < jb) {                                     // full tile: every i < j
    #pragma unroll 4
    for (int l = 0; l < 32; ++l)
      wlo |= ((u32)iou_gt(iboxS[wv][l], iareaS[wv][l], bj, aj)) << l;
    #pragma unroll 4
    for (int l = 0; l < 32; ++l)
      whi |= ((u32)iou_gt(iboxS[wv][l + 32], iareaS[wv][l + 32], bj, aj)) << l;
  } else {                                          // diagonal: strict l < lane
    #pragma unroll 4
    for (int l = 0; l < 32; ++l)
      wlo |= ((u32)((l < lane) && iou_gt(iboxS[wv][l], iareaS[wv][l], bj, aj))) << l;
    #pragma unroll 4
    for (int l = 0; l < 32; ++l)
      whi |= ((u32)((l + 32 < lane) && iou_gt(iboxS[wv][l + 32], iareaS[wv][l + 32], bj, aj))) << l;
  }
  maskT[(b * 16 + c) * kQ + j] = ((u64)whi << 32) | wlo;
}

// Pipelined greedy scan: one block (16 waves) per image; wave k owns chunk k.
// Wave k preloads its fold column into registers, spins for earlier chunks'
// alive sets, folds in-register, then resolves its own chunk by LAYERED
// FIXPOINT: alive = lanes whose every in-chunk suppressor is dead; dead =
// lanes with an alive suppressor. Each round resolves at least the lowest
// unresolved lane (its suppressors are all resolved), so <=64 rounds; for
// random data the suppression DAG is shallow (~3-5 rounds). Cost no longer
// scales with the number of kept boxes.
__global__ void __launch_bounds__(1024) k_scan(const u64* __restrict__ maskT,
                                               const u32* __restrict__ order,
                                               float* __restrict__ out) {
  __shared__ u64 aliveS[16];
  __shared__ u32 doneS;
  const int b = (int)blockIdx.x, tid = (int)threadIdx.x;
  const int lane = tid & 63, k = tid >> 6;          // wave id == chunk id

  // upfront preload, all static-indexed -> registers, one batch of loads
  const u64* mb = maskT + (size_t)(b * 16) * kQ;
  u64 w[15];
  #pragma unroll
  for (int c = 0; c < 15; ++c)
    w[c] = (c < k) ? mb[c * kQ + k * 64 + lane] : 0ull;
  u64 d = mb[k * kQ + k * 64 + lane];               // diag word (bits i<lane only)
  u32 oj = order[b * kQ + k * 64 + lane];

  if (tid == 0) doneS = 0;
  __syncthreads();

  // fold earlier chunks' kept sets as they are published
  bool supp = false;
  #pragma unroll
  for (int c = 0; c < 15; ++c) {
    if (c >= k) break;                              // wave-uniform
    u32 dn;
    do {
      dn = __hip_atomic_load(&doneS, __ATOMIC_ACQUIRE, __HIP_MEMORY_SCOPE_WORKGROUP);
    } while ((int)dn <= c);
    supp = supp || ((w[c] & aliveS[c]) != 0ull);
  }

  // layered fixpoint within chunk k
  u64 dead     = __ballot(supp);                    // cross-chunk-suppressed start dead
  u64 alive    = 0ull;
  u64 resolved = dead;
  for (int it = 0; it < 64 && resolved != ~0ull; ++it) {
    u64 nA = __ballot((d & ~dead) == 0ull) & ~resolved;  // all suppressors dead
    alive    |= nA;
    resolved |= nA;
    u64 nD = __ballot((d & alive) != 0ull) & ~resolved;  // some alive suppressor
    dead     |= nD;
    resolved |= nD;
  }
  if (lane == 0) {
    aliveS[k] = alive;
    __hip_atomic_store(&doneS, (u32)(k + 1), __ATOMIC_RELEASE, __HIP_MEMORY_SCOPE_WORKGROUP);
  }

  out[6 * kBQ + b * kQ + (int)oj] = ((alive >> lane) & 1ull) ? 1.0f : 0.0f;
}

extern "C" void kernel_launch(void* const* d_in, const int* in_sizes, int n_in,
                              void* d_out, int out_size, void* d_ws, size_t ws_size,
                              hipStream_t stream) {
  const float* logits = (const float*)d_in[0];
  const float* pboxes = (const float*)d_in[1];
  const int*   ts     = (const int*)d_in[2];
  float* out = (float*)d_out;

  // ws layout (≈5 MB): maskT 4MB | order 128KB | sbox 512KB | sarea 128KB | keys 256KB
  char* ws = (char*)d_ws;
  u64*    maskT = (u64*)ws;
  u32*    order = (u32*)(ws + (4 << 20));
  float4* sbox  = (float4*)(ws + (4 << 20) + (128 << 10));
  float*  sarea = (float*)(ws + (4 << 20) + (640 << 10));
  u64*    keys  = (u64*)(ws + (4 << 20) + (768 << 10));

  dim3 g1(kBQ / 4), t1(256);
  k_score_box<<<g1, t1, 0, stream>>>(logits, pboxes, ts, out, keys);

  dim3 g2(kB, kQ / 256), t2(256);
  k_rank<<<g2, t2, 0, stream>>>(keys, out, order, sbox, sarea);

  dim3 g3(kB, 34), t3(256);
  k_mask<<<g3, t3, 0, stream>>>(sbox, sarea, maskT);

  k_scan<<<kB, 1024, 0, stream>>>(maskT, order, out);
}

// Round 10
// 59.169 us; speedup vs baseline: 1.5040x; 1.0339x over previous
//
#include <hip/hip_runtime.h>

// DETR-style post-process: softmax scores/labels + box scale + per-image greedy NMS.
// Outputs (flat f32, concatenated): scores[B*Q] | labels[B*Q] | boxes[B*Q*4] | keep[B*Q]
//
// Pipeline (4 graph nodes):
//  k_score_box : per-(b,q) wave softmax/argmax + box conversion + sort key (HBM-bound)
//  k_rank      : counting-rank, LDS-broadcast key scan -> ws          (VALU, cheap)
//  k_mask      : suppression bitmask, div-free exact IoU compare      (VALU-bound)
//  k_scan      : 16-wave pipelined scan + layered fixpoint per chunk  (serial floor)

constexpr int kB  = 32;
constexpr int kQ  = 1024;
constexpr int kNC = 256;
constexpr int kBQ = kB * kQ;

typedef unsigned long long u64;
typedef unsigned int u32;

// IoU > 0.5 with bit-identical result to fdiv_rn(inter,u) > 0.5f, branch-free:
// q = RN32(inter/u) > 0.5 <=> real inter/u > 0.5+2^-25 (midpoint; tie rounds to
// even = 0.5, and exact equality is impossible: it would need a 25-bit mantissa
// ratio). (double)u * (0.5+2^-25) is EXACT (24b x 25b = 49b < 53b), (double)inter
// is exact, so the comparison below is an exact real-number compare. No division,
// no divergent branches.
__device__ __forceinline__ bool iou_gt(const float4& a, float aa,
                                       const float4& b, float ba) {
  float lx = fmaxf(a.x, b.x);
  float ly = fmaxf(a.y, b.y);
  float rx = fminf(a.z, b.z);
  float ry = fminf(a.w, b.w);
  float w  = fmaxf(__fsub_rn(rx, lx), 0.0f);
  float h  = fmaxf(__fsub_rn(ry, ly), 0.0f);
  float inter = __fmul_rn(w, h);
  float u  = fmaxf(__fsub_rn(__fadd_rn(aa, ba), inter), 1e-9f);
  return (double)inter > (double)u * 0.50000002980232238769531250;
}

// One wave (64 lanes) per (b,q): 256 logits -> softmax score/label; box cxcywh->xyxy*scale.
// Also emits the u64 stable-descending sort key for k_rank (from the same score register).
__global__ void k_score_box(const float* __restrict__ logits,
                            const float* __restrict__ pboxes,
                            const int* __restrict__ ts,
                            float* __restrict__ out,
                            u64* __restrict__ keys) {
  int gw   = (int)((blockIdx.x * blockDim.x + threadIdx.x) >> 6);
  int lane = (int)(threadIdx.x & 63);
  if (gw >= kBQ) return;

  float4 v = reinterpret_cast<const float4*>(logits)[gw * (kNC / 4) + lane];

  // foreground (first 255 classes) max + argmax, first-occurrence tie-break
  float fw = (lane == 63) ? -INFINITY : v.w;
  float fm = v.x; int fi = lane * 4;
  if (v.y > fm) { fm = v.y; fi = lane * 4 + 1; }
  if (v.z > fm) { fm = v.z; fi = lane * 4 + 2; }
  if (fw  > fm) { fm = fw;  fi = lane * 4 + 3; }
  for (int off = 32; off > 0; off >>= 1) {
    float om = __shfl_xor(fm, off, 64);
    int   oi = __shfl_xor(fi, off, 64);
    if (om > fm || (om == fm && oi < fi)) { fm = om; fi = oi; }
  }

  float last = __shfl(v.w, 63, 64);     // logit of class 255 (bg)
  float m = fmaxf(fm, last);            // max over all 256 (exact)

  float s = expf(v.x - m) + expf(v.y - m) + expf(v.z - m) + expf(v.w - m);
  for (int off = 32; off > 0; off >>= 1) s += __shfl_xor(s, off, 64);

  if (lane == 0) {
    float sc = expf(fm - m) / s;
    out[gw]       = sc;
    out[kBQ + gw] = (float)fi;
    // stable descending key: scores > 0 -> bit-monotone; low 32 = in-image idx
    keys[gw] = ((u64)(~__float_as_uint(sc)) << 32) | (u32)(gw & (kQ - 1));

    float4 pb = reinterpret_cast<const float4*>(pboxes)[gw];
    int bi = gw >> 10;
    float ih = (float)ts[bi * 2 + 0];
    float iw = (float)ts[bi * 2 + 1];
    float hw = __fmul_rn(0.5f, pb.z);
    float hh = __fmul_rn(0.5f, pb.w);
    float x0 = __fmul_rn(__fsub_rn(pb.x, hw), iw);
    float y0 = __fmul_rn(__fsub_rn(pb.y, hh), ih);
    float x1 = __fmul_rn(__fadd_rn(pb.x, hw), iw);
    float y1 = __fmul_rn(__fadd_rn(pb.y, hh), ih);
    reinterpret_cast<float4*>(out + 2 * kBQ)[gw] = make_float4(x0, y0, x1, y1);
  }
}

// Counting rank: rank_j = #{k : key_k < key_j} over LDS-staged keys (broadcast reads).
// Exactly reproduces stable argsort(-scores). grid (32,4) x 256.
__global__ void __launch_bounds__(256) k_rank(const u64* __restrict__ keys,
                                              const float* __restrict__ out,
                                              u32* __restrict__ order,
                                              float4* __restrict__ sbox,
                                              float* __restrict__ sarea) {
  __shared__ u64 ks[kQ];
  const int b = (int)blockIdx.x, sb = (int)blockIdx.y, tid = (int)threadIdx.x;

  for (int t = tid; t < kQ; t += 256) ks[t] = keys[b * kQ + t];
  __syncthreads();

  const int j = sb * 256 + tid;
  const u64 kj = ks[j];
  int cnt = 0;
  #pragma unroll 8
  for (int k = 0; k < kQ; ++k) cnt += (int)(ks[k] < kj);  // wave-uniform -> broadcast

  float4 bx = reinterpret_cast<const float4*>(out + 2 * kBQ)[b * kQ + j];
  order[b * kQ + cnt] = (u32)j;
  sbox[b * kQ + cnt]  = bx;
  sarea[b * kQ + cnt] = __fmul_rn(__fsub_rn(bx.z, bx.x), __fsub_rn(bx.w, bx.y));
}

// Suppression bitmask, column form: maskT[b][c][j] bit l = (i=c*64+l < j) && IoU(i,j)>thr.
// 4 waves/block, one 64x64 tri-tile per wave: grid (32, 34), r = by*4+wv in [0,136).
__global__ void __launch_bounds__(256) k_mask(const float4* __restrict__ sbox,
                                              const float* __restrict__ sarea,
                                              u64* __restrict__ maskT) {
  const int b = (int)blockIdx.x;
  const int wv = (int)(threadIdx.x >> 6), lane = (int)(threadIdx.x & 63);
  const int r = (int)blockIdx.y * 4 + wv;           // 0..135, all valid

  // linear tri index -> (jb, c), jb >= c
  int jb = (int)((sqrtf((float)(8 * r + 1)) - 1.0f) * 0.5f);
  while ((jb + 1) * (jb + 2) / 2 <= r) ++jb;
  while (jb * (jb + 1) / 2 > r) --jb;
  const int c = r - jb * (jb + 1) / 2;

  __shared__ float4 iboxS[4][64];
  __shared__ float  iareaS[4][64];
  iboxS[wv][lane]  = sbox[b * kQ + c * 64 + lane];
  iareaS[wv][lane] = sarea[b * kQ + c * 64 + lane];
  // wave-private LDS slice: in-wave ds ordering suffices, no block barrier.

  const int j = jb * 64 + lane;
  const float4 bj = sbox[b * kQ + j];
  const float  aj = sarea[b * kQ + j];

  u32 wlo = 0, whi = 0;
  if (c < jb) {                                     // full tile: every i < j
    #pragma unroll 4
    for (int l = 0; l < 32; ++l)
      wlo |= ((u32)iou_gt(iboxS[wv][l], iareaS[wv][l], bj, aj)) << l;
    #pragma unroll 4
    for (int l = 0; l < 32; ++l)
      whi |= ((u32)iou_gt(iboxS[wv][l + 32], iareaS[wv][l + 32], bj, aj)) << l;
  } else {                                          // diagonal: strict l < lane
    #pragma unroll 4
    for (int l = 0; l < 32; ++l)
      wlo |= ((u32)((l < lane) && iou_gt(iboxS[wv][l], iareaS[wv][l], bj, aj))) << l;
    #pragma unroll 4
    for (int l = 0; l < 32; ++l)
      whi |= ((u32)((l + 32 < lane) && iou_gt(iboxS[wv][l + 32], iareaS[wv][l + 32], bj, aj))) << l;
  }
  maskT[(b * 16 + c) * kQ + j] = ((u64)whi << 32) | wlo;
}

// Pipelined greedy scan: one block (16 waves) per image; wave k owns chunk k.
// Wave k preloads its fold column into registers, spins for earlier chunks'
// alive sets, folds in-register, then resolves its own chunk by LAYERED
// FIXPOINT (alive = all suppressors dead; dead = some alive suppressor).
// Each round resolves at least the lowest unresolved lane -> <=64 rounds;
// random-data DAGs are shallow (~3-5 rounds).
__global__ void __launch_bounds__(1024) k_scan(const u64* __restrict__ maskT,
                                               const u32* __restrict__ order,
                                               float* __restrict__ out) {
  __shared__ u64 aliveS[16];
  __shared__ u32 doneS;
  const int b = (int)blockIdx.x, tid = (int)threadIdx.x;
  const int lane = tid & 63, k = tid >> 6;          // wave id == chunk id

  // upfront preload, all static-indexed -> registers, one batch of loads
  const u64* mb = maskT + (size_t)(b * 16) * kQ;
  u64 w[15];
  #pragma unroll
  for (int c = 0; c < 15; ++c)
    w[c] = (c < k) ? mb[c * kQ + k * 64 + lane] : 0ull;
  u64 d = mb[k * kQ + k * 64 + lane];               // diag word (bits i<lane only)
  u32 oj = order[b * kQ + k * 64 + lane];

  if (tid == 0) doneS = 0;
  __syncthreads();

  // fold earlier chunks' kept sets as they are published
  bool supp = false;
  #pragma unroll
  for (int c = 0; c < 15; ++c) {
    if (c >= k) break;                              // wave-uniform
    u32 dn;
    do {
      dn = __hip_atomic_load(&doneS, __ATOMIC_ACQUIRE, __HIP_MEMORY_SCOPE_WORKGROUP);
    } while ((int)dn <= c);
    supp = supp || ((w[c] & aliveS[c]) != 0ull);
  }

  // layered fixpoint within chunk k
  u64 dead     = __ballot(supp);                    // cross-chunk-suppressed start dead
  u64 alive    = 0ull;
  u64 resolved = dead;
  for (int it = 0; it < 64 && resolved != ~0ull; ++it) {
    u64 nA = __ballot((d & ~dead) == 0ull) & ~resolved;  // all suppressors dead
    alive    |= nA;
    resolved |= nA;
    u64 nD = __ballot((d & alive) != 0ull) & ~resolved;  // some alive suppressor
    dead     |= nD;
    resolved |= nD;
  }
  if (lane == 0) {
    aliveS[k] = alive;
    __hip_atomic_store(&doneS, (u32)(k + 1), __ATOMIC_RELEASE, __HIP_MEMORY_SCOPE_WORKGROUP);
  }

  out[6 * kBQ + b * kQ + (int)oj] = ((alive >> lane) & 1ull) ? 1.0f : 0.0f;
}

extern "C" void kernel_launch(void* const* d_in, const int* in_sizes, int n_in,
                              void* d_out, int out_size, void* d_ws, size_t ws_size,
                              hipStream_t stream) {
  const float* logits = (const float*)d_in[0];
  const float* pboxes = (const float*)d_in[1];
  const int*   ts     = (const int*)d_in[2];
  float* out = (float*)d_out;

  // ws layout (≈5 MB): maskT 4MB | order 128KB | sbox 512KB | sarea 128KB | keys 256KB
  char* ws = (char*)d_ws;
  u64*    maskT = (u64*)ws;
  u32*    order = (u32*)(ws + (4 << 20));
  float4* sbox  = (float4*)(ws + (4 << 20) + (128 << 10));
  float*  sarea = (float*)(ws + (4 << 20) + (640 << 10));
  u64*    keys  = (u64*)(ws + (4 << 20) + (768 << 10));

  dim3 g1(kBQ / 4), t1(256);
  k_score_box<<<g1, t1, 0, stream>>>(logits, pboxes, ts, out, keys);

  dim3 g2(kB, kQ / 256), t2(256);
  k_rank<<<g2, t2, 0, stream>>>(keys, out, order, sbox, sarea);

  dim3 g3(kB, 34), t3(256);
  k_mask<<<g3, t3, 0, stream>>>(sbox, sarea, maskT);

  k_scan<<<kB, 1024, 0, stream>>>(maskT, order, out);
}